// Round 20
// baseline (28138.651 us; speedup 1.0000x reference)
//
#include <hip/hip_runtime.h>

typedef unsigned long long u64;
typedef unsigned int u32;

#define NN 200000
#define CC 256
#define KK 100000
#define TILE 2048
#define NB ((NN + TILE - 1) / TILE)   /* 98 */
#define SB ((NN + 255) / 256)         /* 782 */
#define HB 65536                      /* 16-bit bins */

/* output layout (floats) */
#define OFF_X     0
#define OFF_E0    25600000
#define OFF_E1    25700000
#define OFF_PERM  25800000
#define OFF_BATCH 25900000
#define OFF_SC    26000000

/* monotone map: ascending key <=> descending f32 value; equal bits -> same key. */
__device__ __forceinline__ u32 key_of_f32(float s) {
    u32 b = __float_as_uint(s);
    u32 u = b ^ ((b & 0x80000000u) ? 0xFFFFFFFFu : 0x80000000u); /* ascending in s */
    return ~u;                                                   /* descending in s */
}

/* XLA f32 fast-tanh rational approximation, all ops UNFUSED f32 — VERIFIED bit-exact
   vs the np reference (round 12, absmax 0). DO NOT TOUCH. */
__device__ __forceinline__ float xla_tanhf(float x) {
    const float kMax = (float)7.90531110763549805;
    float xc = fminf(fmaxf(x, -kMax), kMax);
    float x2 = __fmul_rn(xc, xc);
    float p = (float)-2.76076847742355e-16;
    p = __fadd_rn(__fmul_rn(p, x2), (float)2.00018790482477e-13);
    p = __fadd_rn(__fmul_rn(p, x2), (float)-8.60467152213735e-11);
    p = __fadd_rn(__fmul_rn(p, x2), (float)5.12229709037114e-08);
    p = __fadd_rn(__fmul_rn(p, x2), (float)1.48572235717979e-05);
    p = __fadd_rn(__fmul_rn(p, x2), (float)6.37261928875436e-04);
    p = __fadd_rn(__fmul_rn(p, x2), (float)4.89352455891786e-03);
    float num = __fmul_rn(xc, p);
    float q = (float)1.19825839466702e-06;
    q = __fadd_rn(__fmul_rn(q, x2), (float)1.18534705686654e-04);
    q = __fadd_rn(__fmul_rn(q, x2), (float)2.26843463243900e-03);
    q = __fadd_rn(__fmul_rn(q, x2), (float)4.89352518554385e-03);
    float t = __fdiv_rn(num, q);
    return (fabsf(x) < 0.0004f) ? x : t;
}

/* ONE THREAD per row — VERIFIED score pipeline (round 12, absmax 0):
   mod-8 FMA lane-chains, adjacent-pairwise tail, unfused +b, XLA tanh.
   NEW: accumulates the 64K-bin histogram (hist pre-zeroed by memset dispatch). */
__global__ void score_kernel(const float* __restrict__ x, const float* __restrict__ w,
                             const float* __restrict__ b, u32* __restrict__ keys,
                             u32* __restrict__ vals, float* __restrict__ scoreF,
                             u32* __restrict__ hist) {
    int i = (int)(blockIdx.x * blockDim.x + threadIdx.x);
    if (i >= NN) return;
    const float4* row = (const float4*)(x + (size_t)i * CC);
    const float4* wv  = (const float4*)w;
    float c0 = 0.f, c1 = 0.f, c2 = 0.f, c3 = 0.f;
    float c4 = 0.f, c5 = 0.f, c6 = 0.f, c7 = 0.f;
#pragma unroll 8
    for (int t = 0; t < 32; ++t) {          /* k = 8t .. 8t+7 */
        float4 a0 = row[2 * t], a1 = row[2 * t + 1];
        float4 w0 = wv[2 * t],  w1 = wv[2 * t + 1];
        c0 = __builtin_fmaf(a0.x, w0.x, c0);
        c1 = __builtin_fmaf(a0.y, w0.y, c1);
        c2 = __builtin_fmaf(a0.z, w0.z, c2);
        c3 = __builtin_fmaf(a0.w, w0.w, c3);
        c4 = __builtin_fmaf(a1.x, w1.x, c4);
        c5 = __builtin_fmaf(a1.y, w1.y, c5);
        c6 = __builtin_fmaf(a1.z, w1.z, c6);
        c7 = __builtin_fmaf(a1.w, w1.w, c7);
    }
    /* adjacent-pairwise tail */
    float d0 = __fadd_rn(c0, c1);
    float d1 = __fadd_rn(c2, c3);
    float d2 = __fadd_rn(c4, c5);
    float d3 = __fadd_rn(c6, c7);
    float e0 = __fadd_rn(d0, d1);
    float e1 = __fadd_rn(d2, d3);
    float dot = __fadd_rn(e0, e1);
    float z = __fadd_rn(dot, b[0]);   /* separate add, unfused */
    float s = xla_tanhf(z);
    u32 key = key_of_f32(s);
    keys[i]   = key;
    vals[i]   = (u32)i;
    scoreF[i] = s;
    atomicAdd(&hist[key >> 16], 1u);
}

/* 2-level exclusive scan of the 64K-bin histogram, all loads coalesced. */
__global__ void scan1(u32* __restrict__ hist, u32* __restrict__ blockTot) {
    __shared__ u32 sb[256];
    int t = threadIdx.x, bk = blockIdx.x;
    u32 v = hist[bk * 256 + t];
    sb[t] = v;
    __syncthreads();
#pragma unroll
    for (int off = 1; off < 256; off <<= 1) {
        u32 u = (t >= off) ? sb[t - off] : 0u;
        __syncthreads();
        sb[t] += u;
        __syncthreads();
    }
    hist[bk * 256 + t] = sb[t] - v;          /* exclusive within chunk */
    if (t == 255) blockTot[bk] = sb[255];
}

__global__ void scan2(const u32* __restrict__ hist, const u32* __restrict__ blockTot,
                      u32* __restrict__ cursor) {
    __shared__ u32 sb[256];
    int t = threadIdx.x, bk = blockIdx.x;
    u32 v = blockTot[t];
    sb[t] = v;
    __syncthreads();
#pragma unroll
    for (int off = 1; off < 256; off <<= 1) {
        u32 u = (t >= off) ? sb[t - off] : 0u;
        __syncthreads();
        sb[t] += u;
        __syncthreads();
    }
    u32 base = sb[bk] - blockTot[bk];        /* exclusive chunk base */
    cursor[bk * 256 + t] = hist[bk * 256 + t] + base;
}

/* scatter by bin-arrival: position = atomic cursor bump. Within-bin order is
   nondeterministic here; the repair kernel canonicalizes it. */
__global__ void scatter16(const u32* __restrict__ keysIn, const u32* __restrict__ valsIn,
                          u32* __restrict__ keysS, u32* __restrict__ valsS,
                          u32* __restrict__ cursor) {
    int i = (int)(blockIdx.x * blockDim.x + threadIdx.x);
    if (i >= NN) return;
    u32 k = keysIn[i], v = valsIn[i];
    u32 r = atomicAdd(&cursor[k >> 16], 1u);
    keysS[r] = k;
    valsS[r] = v;
}

/* canonicalize: sort each equal-bin run in place by (key,val) — identical to
   stable-LSD order (ascending key, ties ascending original index). Leadership and
   run bounds depend only on the bin field, which swaps never change -> race-free.
   Also zeroes mark (keys0 overlay, dead by now). */
__global__ void repair(u32* __restrict__ keysS, u32* __restrict__ valsS,
                       int* __restrict__ mark) {
    int i = (int)(blockIdx.x * blockDim.x + threadIdx.x);
    if (i >= NN) return;
    mark[i] = 0;
    u32 bi = keysS[i] >> 16;
    if (i > 0 && (keysS[i - 1] >> 16) == bi) return;   /* not a run leader */
    int end = i + 1;
    while (end < NN && (keysS[end] >> 16) == bi) ++end;
    if (end == i + 1) return;                          /* singleton */
    for (int a = i; a < end - 1; ++a) {
        u32 bk = keysS[a], bv = valsS[a];
        int bidx = a;
        for (int c = a + 1; c < end; ++c) {
            u32 ck = keysS[c], cv = valsS[c];
            if (ck < bk || (ck == bk && cv < bv)) { bk = ck; bv = cv; bidx = c; }
        }
        if (bidx != a) {
            keysS[bidx] = keysS[a]; valsS[bidx] = valsS[a];
            keysS[a] = bk;          valsS[a] = bv;
        }
    }
}

/* ---------------- post-sort epilogue (r19-proven) ---------------- */

__global__ void gather_sel(const float* __restrict__ x, const u32* __restrict__ vals,
                           const float* __restrict__ scoreF, const int* __restrict__ batch,
                           float* __restrict__ out, int* __restrict__ mark) {
    int kI = (int)((blockIdx.x * blockDim.x + threadIdx.x) >> 6);
    int lane = threadIdx.x & 63;
    if (kI >= KK) return;
    u32 idx = vals[kI];
    const float4* src = (const float4*)(x + (size_t)idx * CC);
    float4* dst = (float4*)(out + OFF_X + (size_t)kI * CC);
    dst[lane] = src[lane];
    if (lane == 0) {
        out[OFF_PERM + kI]  = (float)idx;
        out[OFF_SC + kI]    = scoreF[idx];
        out[OFF_BATCH + kI] = (float)batch[idx];
        mark[idx] = kI + 1;  /* 0 = dropped */
    }
}

__global__ void keep_count(const int* __restrict__ mark, u32* __restrict__ blockCnt) {
    __shared__ u32 wsum[4];
    int wv = threadIdx.x >> 6, lane = threadIdx.x & 63;
    if (threadIdx.x < 4) wsum[threadIdx.x] = 0;
    __syncthreads();
    int base = blockIdx.x * TILE + wv * 512;
    u32 cnt = 0;
#pragma unroll
    for (int e = 0; e < 8; ++e) {
        int i = base + e * 64 + lane;
        if (i < NN && mark[i] == 0) cnt++;
    }
#pragma unroll
    for (int off = 32; off > 0; off >>= 1) cnt += __shfl_xor(cnt, off);
    if (lane == 0) wsum[wv] = cnt;
    __syncthreads();
    if (threadIdx.x == 0) blockCnt[blockIdx.x] = wsum[0] + wsum[1] + wsum[2] + wsum[3];
}

__global__ void edge_scatter(const int* __restrict__ mark, const int* __restrict__ e0,
                             const int* __restrict__ e1, const u32* __restrict__ blockCnt,
                             float* __restrict__ out) {
    __shared__ u32 wbase[4];
    __shared__ u32 wsum2[4];
    int tid = threadIdx.x, wv = tid >> 6, lane = tid & 63, myb = blockIdx.x;
    int base = myb * TILE + wv * 512;

    u32 v = (tid < myb) ? blockCnt[tid] : 0u;   /* myb <= 97 < 256 */
#pragma unroll
    for (int off = 32; off > 0; off >>= 1) v += __shfl_xor(v, off);
    if (lane == 0) wsum2[wv] = v;

    bool flag[8];
    u32 cnt = 0;
#pragma unroll
    for (int e = 0; e < 8; ++e) {
        int i = base + e * 64 + lane;
        flag[e] = (i < NN) && (mark[i] == 0);
        if (flag[e]) cnt++;
    }
    u32 wc = cnt;
#pragma unroll
    for (int off = 32; off > 0; off >>= 1) wc += __shfl_xor(wc, off);
    if (lane == 0) wbase[wv] = wc;
    __syncthreads();
    u32 bOff = wsum2[0] + wsum2[1] + wsum2[2] + wsum2[3];
    if (tid == 0) {
        u32 r = bOff;
#pragma unroll
        for (int w = 0; w < 4; ++w) { u32 c = wbase[w]; wbase[w] = r; r += c; }
    }
    __syncthreads();
    u32 run = wbase[wv];
#pragma unroll
    for (int e = 0; e < 8; ++e) {
        u64 bal = __ballot(flag[e]);
        if (flag[e]) {
            u32 pos = run + (u32)__popcll(bal & ((1ull << lane) - 1ull));
            int i = base + e * 64 + lane;
            int a = mark[e0[i]] - 1; if (a < 0) a = 0;
            int c = mark[e1[i]] - 1; if (c < 0) c = 0;
            out[OFF_E0 + pos] = (float)a;
            out[OFF_E1 + pos] = (float)c;
        }
        run += (u32)__popcll(bal);
    }
}

extern "C" void kernel_launch(void* const* d_in, const int* in_sizes, int n_in,
                              void* d_out, int out_size, void* d_ws, size_t ws_size,
                              hipStream_t stream) {
    (void)in_sizes; (void)n_in; (void)out_size; (void)ws_size;
    const float* x     = (const float*)d_in[0];
    const int*   ei    = (const int*)d_in[1];
    const int*   batch = (const int*)d_in[2];
    const float* w     = (const float*)d_in[3];
    const float* b     = (const float*)d_in[4];
    float* out = (float*)d_out;

    /* ~4.52 MB workspace (<= proven-safe 4.9 MB). mark overlays keys0 (dead after
       scatter16; zeroed by plain stores in repair). */
    char* p = (char*)d_ws;
    u32* keys0 = (u32*)p;            p += (size_t)NN * 4;
    u32* keys1 = (u32*)p;            p += (size_t)NN * 4;
    u32* vals0 = (u32*)p;            p += (size_t)NN * 4;
    u32* vals1 = (u32*)p;            p += (size_t)NN * 4;
    float* scoreF = (float*)p;       p += (size_t)NN * 4;
    u32* hist = (u32*)p;             p += (size_t)HB * 4;
    u32* cursor = (u32*)p;           p += (size_t)HB * 4;
    u32* blockTot = (u32*)p;         p += 256 * 4;
    u32* blockCnt = (u32*)p;         p += (size_t)NB * 4;
    int* mark = (int*)keys0;         /* overlay */

    hipMemsetAsync(hist, 0, (size_t)HB * 4, stream);

    score_kernel<<<SB, 256, 0, stream>>>(x, w, b, keys0, vals0, scoreF, hist);
    scan1<<<HB / 256, 256, 0, stream>>>(hist, blockTot);
    scan2<<<HB / 256, 256, 0, stream>>>(hist, blockTot, cursor);
    scatter16<<<SB, 256, 0, stream>>>(keys0, vals0, keys1, vals1, cursor);
    repair<<<SB, 256, 0, stream>>>(keys1, vals1, mark);
    /* keys1/vals1 now ascending (key,val) == stable-LSD order */

    gather_sel<<<KK * 64 / 256, 256, 0, stream>>>(x, vals1, scoreF, batch, out, mark);
    keep_count<<<NB, 256, 0, stream>>>(mark, blockCnt);
    edge_scatter<<<NB, 256, 0, stream>>>(mark, ei, ei + NN, blockCnt, out);
}

// Round 21
// 175.014 us; speedup vs baseline: 160.7792x; 160.7792x over previous
//
#include <hip/hip_runtime.h>

typedef unsigned long long u64;
typedef unsigned int u32;

#define NN 200000
#define CC 256
#define KK 100000
#define TILE 2048
#define NB ((NN + TILE - 1) / TILE)   /* 98 */

/* output layout (floats) */
#define OFF_X     0
#define OFF_E0    25600000
#define OFF_E1    25700000
#define OFF_PERM  25800000
#define OFF_BATCH 25900000
#define OFF_SC    26000000

/* monotone map: ascending key <=> descending f32 value; equal bits -> same key
   (stable sort then yields ascending original index on ties, matching lax.top_k). */
__device__ __forceinline__ u32 key_of_f32(float s) {
    u32 b = __float_as_uint(s);
    u32 u = b ^ ((b & 0x80000000u) ? 0xFFFFFFFFu : 0x80000000u); /* ascending in s */
    return ~u;                                                   /* descending in s */
}

/* XLA f32 fast-tanh rational approximation, all ops UNFUSED f32 — VERIFIED bit-exact
   vs the np reference (round 12, absmax 0). DO NOT TOUCH. */
__device__ __forceinline__ float xla_tanhf(float x) {
    const float kMax = (float)7.90531110763549805;
    float xc = fminf(fmaxf(x, -kMax), kMax);
    float x2 = __fmul_rn(xc, xc);
    float p = (float)-2.76076847742355e-16;
    p = __fadd_rn(__fmul_rn(p, x2), (float)2.00018790482477e-13);
    p = __fadd_rn(__fmul_rn(p, x2), (float)-8.60467152213735e-11);
    p = __fadd_rn(__fmul_rn(p, x2), (float)5.12229709037114e-08);
    p = __fadd_rn(__fmul_rn(p, x2), (float)1.48572235717979e-05);
    p = __fadd_rn(__fmul_rn(p, x2), (float)6.37261928875436e-04);
    p = __fadd_rn(__fmul_rn(p, x2), (float)4.89352455891786e-03);
    float num = __fmul_rn(xc, p);
    float q = (float)1.19825839466702e-06;
    q = __fadd_rn(__fmul_rn(q, x2), (float)1.18534705686654e-04);
    q = __fadd_rn(__fmul_rn(q, x2), (float)2.26843463243900e-03);
    q = __fadd_rn(__fmul_rn(q, x2), (float)4.89352518554385e-03);
    float t = __fdiv_rn(num, q);
    return (fabsf(x) < 0.0004f) ? x : t;
}

/* ONE THREAD per row — VERIFIED score pipeline (round 12, absmax 0). */
__global__ void score_kernel(const float* __restrict__ x, const float* __restrict__ w,
                             const float* __restrict__ b, u32* __restrict__ keys,
                             u32* __restrict__ vals, float* __restrict__ scoreF) {
    int i = (int)(blockIdx.x * blockDim.x + threadIdx.x);
    if (i >= NN) return;
    const float4* row = (const float4*)(x + (size_t)i * CC);
    const float4* wv  = (const float4*)w;
    float c0 = 0.f, c1 = 0.f, c2 = 0.f, c3 = 0.f;
    float c4 = 0.f, c5 = 0.f, c6 = 0.f, c7 = 0.f;
#pragma unroll 8
    for (int t = 0; t < 32; ++t) {          /* k = 8t .. 8t+7 */
        float4 a0 = row[2 * t], a1 = row[2 * t + 1];
        float4 w0 = wv[2 * t],  w1 = wv[2 * t + 1];
        c0 = __builtin_fmaf(a0.x, w0.x, c0);
        c1 = __builtin_fmaf(a0.y, w0.y, c1);
        c2 = __builtin_fmaf(a0.z, w0.z, c2);
        c3 = __builtin_fmaf(a0.w, w0.w, c3);
        c4 = __builtin_fmaf(a1.x, w1.x, c4);
        c5 = __builtin_fmaf(a1.y, w1.y, c5);
        c6 = __builtin_fmaf(a1.z, w1.z, c6);
        c7 = __builtin_fmaf(a1.w, w1.w, c7);
    }
    /* adjacent-pairwise tail */
    float d0 = __fadd_rn(c0, c1);
    float d1 = __fadd_rn(c2, c3);
    float d2 = __fadd_rn(c4, c5);
    float d3 = __fadd_rn(c6, c7);
    float e0 = __fadd_rn(d0, d1);
    float e1 = __fadd_rn(d2, d3);
    float dot = __fadd_rn(e0, e1);
    float z = __fadd_rn(dot, b[0]);   /* separate add, unfused */
    float s = xla_tanhf(z);
    keys[i]   = key_of_f32(s);
    vals[i]   = (u32)i;
    scoreF[i] = s;
}

/* ---------------- stable LSD radix sort (8-bit digits, 4 passes) — r13-proven ---------- */

__global__ void radix_count(const u32* __restrict__ keys, int shift,
                            u32* __restrict__ counts /*[NB][256]*/, int n) {
    __shared__ u32 hist[256];
    hist[threadIdx.x] = 0;
    __syncthreads();
    int wv = threadIdx.x >> 6, lane = threadIdx.x & 63;
    int base = blockIdx.x * TILE + wv * 512;
#pragma unroll
    for (int e = 0; e < 8; ++e) {
        int i = base + e * 64 + lane;
        if (i < n) {
            u32 d = (keys[i] >> shift) & 255u;
            atomicAdd(&hist[d], 1u);
        }
    }
    __syncthreads();
    counts[blockIdx.x * 256 + threadIdx.x] = hist[threadIdx.x];
}

/* scatter with r13-proven inline global scan + NEW LDS-staged coalesced writes.
   The final global position of each element is ALGEBRAICALLY IDENTICAL to r19:
     old: pos = globalBase[d] + crossWaveRank
     new: lpos = localStart[d] + crossWaveRank (same update discipline),
          write LDS[lpos], then global[gb[d] + (lpos - localStart[d])] = LDS[lpos].
   Ordering/stability unchanged; only write coalescing improves. */
template<bool ZMARK>
__global__ void radix_scatter(const u32* __restrict__ keysIn, const u32* __restrict__ valsIn,
                              u32* __restrict__ keysOut, u32* __restrict__ valsOut,
                              int shift, const u32* __restrict__ counts,
                              int* __restrict__ mark, int n) {
    __shared__ u32 waveCnt[4][256];
    __shared__ u32 scanbuf[256];
    __shared__ u32 tot[256];
    __shared__ u32 gb[256];       /* global digit base for this block */
    __shared__ u32 lstart[256];   /* local (LDS) digit start */
    __shared__ u32 kLDS[TILE];
    __shared__ u32 vLDS[TILE];
    int tid = threadIdx.x;
    int wv = tid >> 6, lane = tid & 63;
    int myb = blockIdx.x;

    /* per-digit: total across all blocks + prefix over blocks before mine (coalesced) */
    u32 myprefix = 0, total = 0;
#pragma unroll 7
    for (int bb = 0; bb < NB; ++bb) {
        u32 c = counts[bb * 256 + tid];
        if (bb < myb) myprefix += c;
        total += c;
    }
    tot[tid] = total;
    scanbuf[tid] = total;
#pragma unroll
    for (int w = 0; w < 4; ++w) waveCnt[w][tid] = 0;
    __syncthreads();
    /* Hillis-Steele inclusive scan over digit totals (global) */
#pragma unroll
    for (int off = 1; off < 256; off <<= 1) {
        u32 v = (tid >= off) ? scanbuf[tid - off] : 0u;
        __syncthreads();
        scanbuf[tid] += v;
        __syncthreads();
    }
    gb[tid] = (scanbuf[tid] - tot[tid]) + myprefix;   /* this block's global digit base */

    int base = myb * TILE + wv * 512;
    u32 k[8];
    u32 vv[8];
    u64 peers[8];
    u32 dg[8];
    int valid[8];
#pragma unroll
    for (int e = 0; e < 8; ++e) {
        int i = base + e * 64 + lane;
        valid[e] = (i < n);
        k[e] = valid[e] ? keysIn[i] : 0u;
        vv[e] = valid[e] ? valsIn[i] : 0u;
        dg[e] = (k[e] >> shift) & 255u;
        if (ZMARK && valid[e]) mark[i] = 0;   /* plain store (proven r17/r18/r19) */
    }
    /* phase 1: per-wave digit totals (ballot peer-mask) — proven machinery */
#pragma unroll
    for (int e = 0; e < 8; ++e) {
        u64 mask = __ballot(valid[e]);
#pragma unroll
        for (int bit = 0; bit < 8; ++bit) {
            u64 bal = __ballot(valid[e] && ((dg[e] >> bit) & 1u));
            mask &= ((dg[e] >> bit) & 1u) ? bal : ~bal;
        }
        peers[e] = mask;
        if (valid[e]) {
            u64 lower = mask & ((1ull << lane) - 1ull);
            if (lower == 0ull)  /* leader of peer group */
                waveCnt[wv][dg[e]] += (u32)__popcll(mask);
        }
    }
    __syncthreads();
    /* block histogram + local exclusive scan (digit-major LDS layout) */
    {
        u32 bh = waveCnt[0][tid] + waveCnt[1][tid] + waveCnt[2][tid] + waveCnt[3][tid];
        scanbuf[tid] = bh;
        tot[tid] = bh;
    }
    __syncthreads();
#pragma unroll
    for (int off = 1; off < 256; off <<= 1) {
        u32 v = (tid >= off) ? scanbuf[tid - off] : 0u;
        __syncthreads();
        scanbuf[tid] += v;
        __syncthreads();
    }
    lstart[tid] = scanbuf[tid] - tot[tid];
    __syncthreads();
    /* cross-wave LOCAL bases (same sequential discipline as r19's global version) */
    {
        u32 r = lstart[tid];
#pragma unroll
        for (int w = 0; w < 4; ++w) { u32 c = waveCnt[w][tid]; waveCnt[w][tid] = r; r += c; }
    }
    __syncthreads();
    /* phase 2a: scatter into LDS at local digit-sorted positions */
#pragma unroll
    for (int e = 0; e < 8; ++e) {
        if (valid[e]) {
            u64 mask = peers[e];
            u64 lower = mask & ((1ull << lane) - 1ull);
            u32 rk = (u32)__popcll(lower);
            u32 lpos = waveCnt[wv][dg[e]] + rk;
            kLDS[lpos] = k[e];
            vLDS[lpos] = vv[e];
            if (lower == 0ull) waveCnt[wv][dg[e]] += (u32)__popcll(mask);
        }
    }
    __syncthreads();
    /* phase 2b: linear LDS read -> coalesced global writes.
       valid LDS slots are [0, vcnt) where vcnt = elements in this block. */
    int vcnt = n - myb * TILE; if (vcnt > TILE) vcnt = TILE;
#pragma unroll
    for (int e = 0; e < 8; ++e) {
        int p = e * 256 + tid;
        if (p < vcnt) {
            u32 kk = kLDS[p];
            u32 d = (kk >> shift) & 255u;
            u32 gpos = gb[d] + ((u32)p - lstart[d]);
            keysOut[gpos] = kk;
            valsOut[gpos] = vLDS[p];
        }
    }
}

/* ---------------- post-sort epilogue (r19-proven) ---------------- */

__global__ void gather_sel(const float* __restrict__ x, const u32* __restrict__ vals,
                           const float* __restrict__ scoreF, const int* __restrict__ batch,
                           float* __restrict__ out, int* __restrict__ mark) {
    int kI = (int)((blockIdx.x * blockDim.x + threadIdx.x) >> 6);
    int lane = threadIdx.x & 63;
    if (kI >= KK) return;
    u32 idx = vals[kI];
    const float4* src = (const float4*)(x + (size_t)idx * CC);
    float4* dst = (float4*)(out + OFF_X + (size_t)kI * CC);
    dst[lane] = src[lane];
    if (lane == 0) {
        out[OFF_PERM + kI]  = (float)idx;
        out[OFF_SC + kI]    = scoreF[idx];
        out[OFF_BATCH + kI] = (float)batch[idx];
        mark[idx] = kI + 1;  /* 0 = dropped */
    }
}

__global__ void keep_count(const int* __restrict__ mark, u32* __restrict__ blockCnt) {
    __shared__ u32 wsum[4];
    int wv = threadIdx.x >> 6, lane = threadIdx.x & 63;
    if (threadIdx.x < 4) wsum[threadIdx.x] = 0;
    __syncthreads();
    int base = blockIdx.x * TILE + wv * 512;
    u32 cnt = 0;
#pragma unroll
    for (int e = 0; e < 8; ++e) {
        int i = base + e * 64 + lane;
        if (i < NN && mark[i] == 0) cnt++;
    }
#pragma unroll
    for (int off = 32; off > 0; off >>= 1) cnt += __shfl_xor(cnt, off);
    if (lane == 0) wsum[wv] = cnt;
    __syncthreads();
    if (threadIdx.x == 0) blockCnt[blockIdx.x] = wsum[0] + wsum[1] + wsum[2] + wsum[3];
}

__global__ void edge_scatter(const int* __restrict__ mark, const int* __restrict__ e0,
                             const int* __restrict__ e1, const u32* __restrict__ blockCnt,
                             float* __restrict__ out) {
    __shared__ u32 wbase[4];
    __shared__ u32 wsum2[4];
    int tid = threadIdx.x, wv = tid >> 6, lane = tid & 63, myb = blockIdx.x;
    int base = myb * TILE + wv * 512;

    u32 v = (tid < myb) ? blockCnt[tid] : 0u;   /* myb <= 97 < 256 */
#pragma unroll
    for (int off = 32; off > 0; off >>= 1) v += __shfl_xor(v, off);
    if (lane == 0) wsum2[wv] = v;

    bool flag[8];
    u32 cnt = 0;
#pragma unroll
    for (int e = 0; e < 8; ++e) {
        int i = base + e * 64 + lane;
        flag[e] = (i < NN) && (mark[i] == 0);
        if (flag[e]) cnt++;
    }
    u32 wc = cnt;
#pragma unroll
    for (int off = 32; off > 0; off >>= 1) wc += __shfl_xor(wc, off);
    if (lane == 0) wbase[wv] = wc;
    __syncthreads();
    u32 bOff = wsum2[0] + wsum2[1] + wsum2[2] + wsum2[3];
    if (tid == 0) {
        u32 r = bOff;
#pragma unroll
        for (int w = 0; w < 4; ++w) { u32 c = wbase[w]; wbase[w] = r; r += c; }
    }
    __syncthreads();
    u32 run = wbase[wv];
#pragma unroll
    for (int e = 0; e < 8; ++e) {
        u64 bal = __ballot(flag[e]);
        if (flag[e]) {
            u32 pos = run + (u32)__popcll(bal & ((1ull << lane) - 1ull));
            int i = base + e * 64 + lane;
            int a = mark[e0[i]] - 1; if (a < 0) a = 0;
            int c = mark[e1[i]] - 1; if (c < 0) c = 0;
            out[OFF_E0 + pos] = (float)a;
            out[OFF_E1 + pos] = (float)c;
        }
        run += (u32)__popcll(bal);
    }
}

extern "C" void kernel_launch(void* const* d_in, const int* in_sizes, int n_in,
                              void* d_out, int out_size, void* d_ws, size_t ws_size,
                              hipStream_t stream) {
    (void)in_sizes; (void)n_in; (void)out_size; (void)ws_size;
    const float* x     = (const float*)d_in[0];
    const int*   ei    = (const int*)d_in[1];
    const int*   batch = (const int*)d_in[2];
    const float* w     = (const float*)d_in[3];
    const float* b     = (const float*)d_in[4];
    float* out = (float*)d_out;

    /* proven-safe ~4.9 MB workspace footprint (r13/r19 layout) */
    char* p = (char*)d_ws;
    u32* keys0 = (u32*)p;            p += (size_t)NN * 4;
    u32* keys1 = (u32*)p;            p += (size_t)NN * 4;
    u32* vals0 = (u32*)p;            p += (size_t)NN * 4;
    u32* vals1 = (u32*)p;            p += (size_t)NN * 4;
    float* scoreF = (float*)p;       p += (size_t)NN * 4;
    int* mark = (int*)p;             p += (size_t)NN * 4;
    u32* counts = (u32*)p;           p += (size_t)NB * 256 * 4;
    u32* blockCnt = (u32*)p;         p += (size_t)NB * 4;

    score_kernel<<<(NN + 255) / 256, 256, 0, stream>>>(x, w, b, keys0, vals0, scoreF);

    /* 4 passes x 8 bits (r19-proven structure); pass 3 zeroes mark inline */
    radix_count<<<NB, 256, 0, stream>>>(keys0, 0, counts, NN);
    radix_scatter<false><<<NB, 256, 0, stream>>>(keys0, vals0, keys1, vals1, 0, counts,
                                                 nullptr, NN);
    radix_count<<<NB, 256, 0, stream>>>(keys1, 8, counts, NN);
    radix_scatter<false><<<NB, 256, 0, stream>>>(keys1, vals1, keys0, vals0, 8, counts,
                                                 nullptr, NN);
    radix_count<<<NB, 256, 0, stream>>>(keys0, 16, counts, NN);
    radix_scatter<false><<<NB, 256, 0, stream>>>(keys0, vals0, keys1, vals1, 16, counts,
                                                 nullptr, NN);
    radix_count<<<NB, 256, 0, stream>>>(keys1, 24, counts, NN);
    radix_scatter<true><<<NB, 256, 0, stream>>>(keys1, vals1, keys0, vals0, 24, counts,
                                                mark, NN);
    /* final sorted pairs in keys0/vals0; mark zeroed */

    gather_sel<<<KK * 64 / 256, 256, 0, stream>>>(x, vals0, scoreF, batch, out, mark);
    keep_count<<<NB, 256, 0, stream>>>(mark, blockCnt);
    edge_scatter<<<NB, 256, 0, stream>>>(mark, ei, ei + NN, blockCnt, out);
}

// Round 22
// 150.149 us; speedup vs baseline: 187.4046x; 1.1656x over previous
//
#include <hip/hip_runtime.h>

typedef unsigned long long u64;
typedef unsigned int u32;

#define NN 200000
#define CC 256
#define KK 100000
#define TILE 2048
#define NB ((NN + TILE - 1) / TILE)   /* 98 */

/* output layout (floats) */
#define OFF_X     0
#define OFF_E0    25600000
#define OFF_E1    25700000
#define OFF_PERM  25800000
#define OFF_BATCH 25900000
#define OFF_SC    26000000

/* monotone map: ascending key <=> descending f32 value; equal bits -> same key
   (stable sort then yields ascending original index on ties, matching lax.top_k). */
__device__ __forceinline__ u32 key_of_f32(float s) {
    u32 b = __float_as_uint(s);
    u32 u = b ^ ((b & 0x80000000u) ? 0xFFFFFFFFu : 0x80000000u); /* ascending in s */
    return ~u;                                                   /* descending in s */
}

/* XLA f32 fast-tanh rational approximation, all ops UNFUSED f32 — VERIFIED bit-exact
   vs the np reference (round 12, absmax 0). DO NOT TOUCH. */
__device__ __forceinline__ float xla_tanhf(float x) {
    const float kMax = (float)7.90531110763549805;
    float xc = fminf(fmaxf(x, -kMax), kMax);
    float x2 = __fmul_rn(xc, xc);
    float p = (float)-2.76076847742355e-16;
    p = __fadd_rn(__fmul_rn(p, x2), (float)2.00018790482477e-13);
    p = __fadd_rn(__fmul_rn(p, x2), (float)-8.60467152213735e-11);
    p = __fadd_rn(__fmul_rn(p, x2), (float)5.12229709037114e-08);
    p = __fadd_rn(__fmul_rn(p, x2), (float)1.48572235717979e-05);
    p = __fadd_rn(__fmul_rn(p, x2), (float)6.37261928875436e-04);
    p = __fadd_rn(__fmul_rn(p, x2), (float)4.89352455891786e-03);
    float num = __fmul_rn(xc, p);
    float q = (float)1.19825839466702e-06;
    q = __fadd_rn(__fmul_rn(q, x2), (float)1.18534705686654e-04);
    q = __fadd_rn(__fmul_rn(q, x2), (float)2.26843463243900e-03);
    q = __fadd_rn(__fmul_rn(q, x2), (float)4.89352518554385e-03);
    float t = __fdiv_rn(num, q);
    return (fabsf(x) < 0.0004f) ? x : t;
}

/* 8 LANES per row — BIT-EXACT reformulation of the verified score pipeline:
   lane j owns chain c_j (k == j mod 8), 32 sequential v_fma_f32 — identical op
   sequence per chain. Tail via 3 xor-shuffles taking lane-0's fadd(own, other):
     s1(0)=fadd(c0,c1), s2(0)=fadd(s1(0),s1(2))=fadd(fadd(c0,c1),fadd(c2,c3)),
     s3(0)=fadd(s2(0),s2(4)) == verified adjacent-pairwise tail. Lane 0 writes. */
__global__ void score_kernel(const float* __restrict__ x, const float* __restrict__ w,
                             const float* __restrict__ b, u32* __restrict__ keys,
                             u32* __restrict__ vals, float* __restrict__ scoreF) {
    int tid = threadIdx.x;
    int row = (int)(blockIdx.x * 32 + (tid >> 3));   /* grid 6250*32 = 200000 exact */
    int j = tid & 7;
    const float* xr = x + (size_t)row * CC;
    float c = 0.f;
#pragma unroll 8
    for (int t = 0; t < 32; ++t)
        c = __builtin_fmaf(xr[t * 8 + j], w[t * 8 + j], c);
    float s1 = __fadd_rn(c, __shfl_xor(c, 1));
    float s2 = __fadd_rn(s1, __shfl_xor(s1, 2));
    float dot = __fadd_rn(s2, __shfl_xor(s2, 4));
    if (j == 0) {
        float z = __fadd_rn(dot, b[0]);   /* separate add, unfused */
        float s = xla_tanhf(z);
        keys[row]   = key_of_f32(s);
        vals[row]   = (u32)row;
        scoreF[row] = s;
    }
}

/* ---------------- stable LSD radix sort (8-bit digits, 4 passes) — r13-proven ---------- */

__global__ void radix_count(const u32* __restrict__ keys, int shift,
                            u32* __restrict__ counts /*[NB][256]*/, int n) {
    __shared__ u32 hist[256];
    hist[threadIdx.x] = 0;
    __syncthreads();
    int wv = threadIdx.x >> 6, lane = threadIdx.x & 63;
    int base = blockIdx.x * TILE + wv * 512;
#pragma unroll
    for (int e = 0; e < 8; ++e) {
        int i = base + e * 64 + lane;
        if (i < n) {
            u32 d = (keys[i] >> shift) & 255u;
            atomicAdd(&hist[d], 1u);
        }
    }
    __syncthreads();
    counts[blockIdx.x * 256 + threadIdx.x] = hist[threadIdx.x];
}

/* scatter: r13-proven inline global scan + r21-proven LDS-staged coalesced writes.
   WRITEKEYS=false on the final pass skips the dead keysOut stream. */
template<bool ZMARK, bool WRITEKEYS>
__global__ void radix_scatter(const u32* __restrict__ keysIn, const u32* __restrict__ valsIn,
                              u32* __restrict__ keysOut, u32* __restrict__ valsOut,
                              int shift, const u32* __restrict__ counts,
                              int* __restrict__ mark, int n) {
    __shared__ u32 waveCnt[4][256];
    __shared__ u32 scanbuf[256];
    __shared__ u32 tot[256];
    __shared__ u32 gb[256];       /* global digit base for this block */
    __shared__ u32 lstart[256];   /* local (LDS) digit start */
    __shared__ u32 kLDS[TILE];
    __shared__ u32 vLDS[TILE];
    int tid = threadIdx.x;
    int wv = tid >> 6, lane = tid & 63;
    int myb = blockIdx.x;

    /* per-digit: total across all blocks + prefix over blocks before mine (coalesced) */
    u32 myprefix = 0, total = 0;
#pragma unroll 7
    for (int bb = 0; bb < NB; ++bb) {
        u32 c = counts[bb * 256 + tid];
        if (bb < myb) myprefix += c;
        total += c;
    }
    tot[tid] = total;
    scanbuf[tid] = total;
#pragma unroll
    for (int w = 0; w < 4; ++w) waveCnt[w][tid] = 0;
    __syncthreads();
    /* Hillis-Steele inclusive scan over digit totals (global) */
#pragma unroll
    for (int off = 1; off < 256; off <<= 1) {
        u32 v = (tid >= off) ? scanbuf[tid - off] : 0u;
        __syncthreads();
        scanbuf[tid] += v;
        __syncthreads();
    }
    gb[tid] = (scanbuf[tid] - tot[tid]) + myprefix;   /* this block's global digit base */

    int base = myb * TILE + wv * 512;
    u32 k[8];
    u32 vv[8];
    u64 peers[8];
    u32 dg[8];
    int valid[8];
#pragma unroll
    for (int e = 0; e < 8; ++e) {
        int i = base + e * 64 + lane;
        valid[e] = (i < n);
        k[e] = valid[e] ? keysIn[i] : 0u;
        vv[e] = valid[e] ? valsIn[i] : 0u;
        dg[e] = (k[e] >> shift) & 255u;
        if (ZMARK && valid[e]) mark[i] = 0;   /* plain store (proven r17-r21) */
    }
    /* phase 1: per-wave digit totals (ballot peer-mask) — proven machinery */
#pragma unroll
    for (int e = 0; e < 8; ++e) {
        u64 mask = __ballot(valid[e]);
#pragma unroll
        for (int bit = 0; bit < 8; ++bit) {
            u64 bal = __ballot(valid[e] && ((dg[e] >> bit) & 1u));
            mask &= ((dg[e] >> bit) & 1u) ? bal : ~bal;
        }
        peers[e] = mask;
        if (valid[e]) {
            u64 lower = mask & ((1ull << lane) - 1ull);
            if (lower == 0ull)  /* leader of peer group */
                waveCnt[wv][dg[e]] += (u32)__popcll(mask);
        }
    }
    __syncthreads();
    /* block histogram + local exclusive scan */
    {
        u32 bh = waveCnt[0][tid] + waveCnt[1][tid] + waveCnt[2][tid] + waveCnt[3][tid];
        scanbuf[tid] = bh;
        tot[tid] = bh;
    }
    __syncthreads();
#pragma unroll
    for (int off = 1; off < 256; off <<= 1) {
        u32 v = (tid >= off) ? scanbuf[tid - off] : 0u;
        __syncthreads();
        scanbuf[tid] += v;
        __syncthreads();
    }
    lstart[tid] = scanbuf[tid] - tot[tid];
    __syncthreads();
    /* cross-wave LOCAL bases (same sequential discipline as the proven global form) */
    {
        u32 r = lstart[tid];
#pragma unroll
        for (int w = 0; w < 4; ++w) { u32 c = waveCnt[w][tid]; waveCnt[w][tid] = r; r += c; }
    }
    __syncthreads();
    /* phase 2a: scatter into LDS at local digit-sorted positions */
#pragma unroll
    for (int e = 0; e < 8; ++e) {
        if (valid[e]) {
            u64 mask = peers[e];
            u64 lower = mask & ((1ull << lane) - 1ull);
            u32 rk = (u32)__popcll(lower);
            u32 lpos = waveCnt[wv][dg[e]] + rk;
            kLDS[lpos] = k[e];
            vLDS[lpos] = vv[e];
            if (lower == 0ull) waveCnt[wv][dg[e]] += (u32)__popcll(mask);
        }
    }
    __syncthreads();
    /* phase 2b: linear LDS read -> coalesced global writes */
    int vcnt = n - myb * TILE; if (vcnt > TILE) vcnt = TILE;
#pragma unroll
    for (int e = 0; e < 8; ++e) {
        int p = e * 256 + tid;
        if (p < vcnt) {
            u32 kk = kLDS[p];
            u32 d = (kk >> shift) & 255u;
            u32 gpos = gb[d] + ((u32)p - lstart[d]);
            if (WRITEKEYS) keysOut[gpos] = kk;
            valsOut[gpos] = vLDS[p];
        }
    }
}

/* ---------------- post-sort epilogue (r19-proven) ---------------- */

__global__ void gather_sel(const float* __restrict__ x, const u32* __restrict__ vals,
                           const float* __restrict__ scoreF, const int* __restrict__ batch,
                           float* __restrict__ out, int* __restrict__ mark) {
    int kI = (int)((blockIdx.x * blockDim.x + threadIdx.x) >> 6);
    int lane = threadIdx.x & 63;
    if (kI >= KK) return;
    u32 idx = vals[kI];
    const float4* src = (const float4*)(x + (size_t)idx * CC);
    float4* dst = (float4*)(out + OFF_X + (size_t)kI * CC);
    dst[lane] = src[lane];
    if (lane == 0) {
        out[OFF_PERM + kI]  = (float)idx;
        out[OFF_SC + kI]    = scoreF[idx];
        out[OFF_BATCH + kI] = (float)batch[idx];
        mark[idx] = kI + 1;  /* 0 = dropped */
    }
}

__global__ void keep_count(const int* __restrict__ mark, u32* __restrict__ blockCnt) {
    __shared__ u32 wsum[4];
    int wv = threadIdx.x >> 6, lane = threadIdx.x & 63;
    if (threadIdx.x < 4) wsum[threadIdx.x] = 0;
    __syncthreads();
    int base = blockIdx.x * TILE + wv * 512;
    u32 cnt = 0;
#pragma unroll
    for (int e = 0; e < 8; ++e) {
        int i = base + e * 64 + lane;
        if (i < NN && mark[i] == 0) cnt++;
    }
#pragma unroll
    for (int off = 32; off > 0; off >>= 1) cnt += __shfl_xor(cnt, off);
    if (lane == 0) wsum[wv] = cnt;
    __syncthreads();
    if (threadIdx.x == 0) blockCnt[blockIdx.x] = wsum[0] + wsum[1] + wsum[2] + wsum[3];
}

__global__ void edge_scatter(const int* __restrict__ mark, const int* __restrict__ e0,
                             const int* __restrict__ e1, const u32* __restrict__ blockCnt,
                             float* __restrict__ out) {
    __shared__ u32 wbase[4];
    __shared__ u32 wsum2[4];
    int tid = threadIdx.x, wv = tid >> 6, lane = tid & 63, myb = blockIdx.x;
    int base = myb * TILE + wv * 512;

    u32 v = (tid < myb) ? blockCnt[tid] : 0u;   /* myb <= 97 < 256 */
#pragma unroll
    for (int off = 32; off > 0; off >>= 1) v += __shfl_xor(v, off);
    if (lane == 0) wsum2[wv] = v;

    bool flag[8];
    u32 cnt = 0;
#pragma unroll
    for (int e = 0; e < 8; ++e) {
        int i = base + e * 64 + lane;
        flag[e] = (i < NN) && (mark[i] == 0);
        if (flag[e]) cnt++;
    }
    u32 wc = cnt;
#pragma unroll
    for (int off = 32; off > 0; off >>= 1) wc += __shfl_xor(wc, off);
    if (lane == 0) wbase[wv] = wc;
    __syncthreads();
    u32 bOff = wsum2[0] + wsum2[1] + wsum2[2] + wsum2[3];
    if (tid == 0) {
        u32 r = bOff;
#pragma unroll
        for (int w = 0; w < 4; ++w) { u32 c = wbase[w]; wbase[w] = r; r += c; }
    }
    __syncthreads();
    u32 run = wbase[wv];
#pragma unroll
    for (int e = 0; e < 8; ++e) {
        u64 bal = __ballot(flag[e]);
        if (flag[e]) {
            u32 pos = run + (u32)__popcll(bal & ((1ull << lane) - 1ull));
            int i = base + e * 64 + lane;
            int a = mark[e0[i]] - 1; if (a < 0) a = 0;
            int c = mark[e1[i]] - 1; if (c < 0) c = 0;
            out[OFF_E0 + pos] = (float)a;
            out[OFF_E1 + pos] = (float)c;
        }
        run += (u32)__popcll(bal);
    }
}

extern "C" void kernel_launch(void* const* d_in, const int* in_sizes, int n_in,
                              void* d_out, int out_size, void* d_ws, size_t ws_size,
                              hipStream_t stream) {
    (void)in_sizes; (void)n_in; (void)out_size; (void)ws_size;
    const float* x     = (const float*)d_in[0];
    const int*   ei    = (const int*)d_in[1];
    const int*   batch = (const int*)d_in[2];
    const float* w     = (const float*)d_in[3];
    const float* b     = (const float*)d_in[4];
    float* out = (float*)d_out;

    /* proven-safe ~4.9 MB workspace footprint (r13/r19/r21 layout) */
    char* p = (char*)d_ws;
    u32* keys0 = (u32*)p;            p += (size_t)NN * 4;
    u32* keys1 = (u32*)p;            p += (size_t)NN * 4;
    u32* vals0 = (u32*)p;            p += (size_t)NN * 4;
    u32* vals1 = (u32*)p;            p += (size_t)NN * 4;
    float* scoreF = (float*)p;       p += (size_t)NN * 4;
    int* mark = (int*)p;             p += (size_t)NN * 4;
    u32* counts = (u32*)p;           p += (size_t)NB * 256 * 4;
    u32* blockCnt = (u32*)p;         p += (size_t)NB * 4;

    score_kernel<<<NN / 32, 256, 0, stream>>>(x, w, b, keys0, vals0, scoreF);

    /* 4 passes x 8 bits (r21-proven structure); pass 3: zero mark inline, skip keys */
    radix_count<<<NB, 256, 0, stream>>>(keys0, 0, counts, NN);
    radix_scatter<false, true><<<NB, 256, 0, stream>>>(keys0, vals0, keys1, vals1, 0,
                                                       counts, nullptr, NN);
    radix_count<<<NB, 256, 0, stream>>>(keys1, 8, counts, NN);
    radix_scatter<false, true><<<NB, 256, 0, stream>>>(keys1, vals1, keys0, vals0, 8,
                                                       counts, nullptr, NN);
    radix_count<<<NB, 256, 0, stream>>>(keys0, 16, counts, NN);
    radix_scatter<false, true><<<NB, 256, 0, stream>>>(keys0, vals0, keys1, vals1, 16,
                                                       counts, nullptr, NN);
    radix_count<<<NB, 256, 0, stream>>>(keys1, 24, counts, NN);
    radix_scatter<true, false><<<NB, 256, 0, stream>>>(keys1, vals1, keys0, vals0, 24,
                                                       counts, mark, NN);
    /* final sorted vals in vals0; mark zeroed */

    gather_sel<<<KK * 64 / 256, 256, 0, stream>>>(x, vals0, scoreF, batch, out, mark);
    keep_count<<<NB, 256, 0, stream>>>(mark, blockCnt);
    edge_scatter<<<NB, 256, 0, stream>>>(mark, ei, ei + NN, blockCnt, out);
}